// Round 10
// baseline (135.553 us; speedup 1.0000x reference)
//
#include <hip/hip_runtime.h>
#include <math.h>

typedef float v2f __attribute__((ext_vector_type(2)));  // -> v_pk_*_f32

static __device__ __forceinline__ v2f sp(float s) { v2f r; r.x = s; r.y = s; return r; }

// --- GF(2)-linear index helpers (fold to constants at literal args) ---
// LDS bank swizzle: slot = i ^ ((i>>4)&15)  (involution)
__device__ __forceinline__ int sig(int i) { return i ^ ((i >> 4) & 15); }
// sig(finv(r)), r in [0,16): finv(c) = ((c ^ (c<<1)) & 0xFFF) ^ (bit11(c)*3)
__device__ __forceinline__ int gk(int r) {
    int j = (r ^ (r << 1)) & 0xFFF;
    return j ^ ((j >> 4) & 15);
}
// sig(finv(r<<8)), r in [0,16)
__device__ __forceinline__ int mk(int r) {
    int c = r << 8;
    int j = ((c ^ (c << 1)) & 0xFFF) ^ ((c >> 11) * 3);
    return j ^ ((j >> 4) & 15);
}

// ---------- Kernel A: params -> factored U3 (rot + lambda/phi phasors) ----------
// One thread per (batch, group). Output per (b,g): 24 floats at ws + b*96 + g*32:
//   [0..7]  (ct,st) x4 qubits      R  = [[ct,-st],[st,ct]]
//   [8..15] (cos l, sin l) x4      Lam = diag(1, e^{il})
//   [16..23](cos f, sin f) x4      Phi = diag(1, e^{if})
// U3 = Phi * R * Lam. ws total = 2048*96*4 = 786432 B (proven size).
__global__ __attribute__((amdgpu_flat_work_group_size(256, 256)))
void qparam_kernel(const float* __restrict__ x, const float* __restrict__ rw,
                   const float* __restrict__ rb, float* __restrict__ uo, int total3)
{
    const int g = blockIdx.x * 256 + threadIdx.x;   // g = b*3 + grp
    if (g >= total3) return;
    const int b = g / 3, grp = g - 3 * b;
    float* o = uo + b * 96 + grp * 32;
    #pragma unroll
    for (int q = 0; q < 4; ++q) {
        const int c = grp * 4 + q;
        const float4 xv = ((const float4*)x)[b * 12 + c];
        float prm[3];
        #pragma unroll
        for (int p = 0; p < 3; ++p) {
            const float4 wv = ((const float4*)rw)[c * 3 + p];
            prm[p] = rb[c * 3 + p] + wv.x * xv.x + wv.y * xv.y + wv.z * xv.z + wv.w * xv.w;
        }
        float st_, ct_; sincosf(0.5f * prm[0], &st_, &ct_);
        float sf_, cf_; sincosf(prm[1], &sf_, &cf_);
        float sl_, cl_; sincosf(prm[2], &sl_, &cl_);
        ((float2*)o)[q]     = make_float2(ct_, st_);
        ((float2*)o)[4 + q] = make_float2(cl_, sl_);
        ((float2*)o)[8 + q] = make_float2(cf_, sf_);
    }
}

// Apply a factored 4-gate group to the 16-amp register subcube.
// p: block-uniform pointer (SGPR loads). doL/doP: wave-uniform skips.
__device__ __forceinline__ void apply4f(v2f v[16], const float* __restrict__ p,
                                        bool doL, bool doP) {
    if (doL) {   // Lambda: amps with bit b set *= e^{i l_b}  (scalar mul/fma, no swaps)
        #pragma unroll
        for (int b = 0; b < 4; ++b) {
            const float cr = p[8 + 2 * b], ci = p[9 + 2 * b];
            const int m = 1 << b;
            #pragma unroll
            for (int j = 0; j < 16; ++j) if (j & m) {
                const float re = v[j].x, im = v[j].y;
                v[j].x = cr * re - ci * im;
                v[j].y = cr * im + ci * re;
            }
        }
    }
    // R: real Givens rotations -> pure v_pk_mul/v_pk_fma, zero swap ops
    #pragma unroll
    for (int b = 0; b < 4; ++b) {
        const float ct = p[2 * b], st = p[2 * b + 1];
        const int m = 1 << b;
        #pragma unroll
        for (int j = 0; j < 16; ++j) if (!(j & m)) {
            const v2f a0 = v[j], a1 = v[j | m];
            v[j]     = sp(ct) * a0 - sp(st) * a1;
            v[j | m] = sp(st) * a0 + sp(ct) * a1;
        }
    }
    if (doP) {   // Phi: amps with bit b set *= e^{i f_b}
        #pragma unroll
        for (int b = 0; b < 4; ++b) {
            const float cr = p[16 + 2 * b], ci = p[17 + 2 * b];
            const int m = 1 << b;
            #pragma unroll
            for (int j = 0; j < 16; ++j) if (j & m) {
                const float re = v[j].x, im = v[j].y;
                v[j].x = cr * re - ci * im;
                v[j].y = cr * im + ci * re;
            }
        }
    }
}

// ---------- Kernel B: statevector sim + measurement + MLP head ----------
__global__ __attribute__((amdgpu_flat_work_group_size(256, 256), amdgpu_waves_per_eu(4, 5)))
void qreup_kernel(const float* __restrict__ uin,  // [B,96] factored gate data
                  const float* __restrict__ w1,   // [64,12]
                  const float* __restrict__ b1,   // [64]
                  const float* __restrict__ w2,   // [256,64]
                  const float* __restrict__ b2,   // [256]
                  float* __restrict__ out)        // [B,256]
{
    __shared__ v2f st[4096];                      // 32768 B, swizzled layout sig(i)

    const int t = threadIdx.x;
    const int b = blockIdx.x;
    const float* __restrict__ ub = uin + b * 96;  // block-uniform gate table

    // slot bases (GF(2)-linear decompositions of the swizzled layout)
    const int base0 = (t << 4) | (t & 15);         // G0: slot = base0 ^ j
    const int base1 = ((t >> 4) << 8) | (t & 15);  // G1: slot = base1 ^ (17j)
    const int base2 = t ^ (t >> 4);                // G2: slot = base2 ^ (j<<8)
    const int a_ = t << 4;                         // gather base: sig(finv(t<<4))
    const int gj = ((a_ ^ (a_ << 1)) & 0xFFF) ^ ((a_ >> 11) * 3);
    const int gbase = gj ^ ((gj >> 4) & 15);
    const int mbase = sig((t ^ (t << 1)) & 0xFFF); // sig(finv(t)), t<256

    #pragma unroll 1
    for (int L = 0; L < 3; ++L) {
        v2f v[16];
        // G0 (wires 0-3); previous layer's CNOT ring folded into the gather
        if (L == 0) {
            #pragma unroll
            for (int r = 0; r < 16; ++r) v[r] = sp(0.0f);
            if (t == 0) v[0].x = 1.0f;
        } else {
            #pragma unroll
            for (int r = 0; r < 16; ++r) v[r] = st[gbase ^ gk(r)];
        }
        apply4f(v, ub, L != 0, true);   // Lambda trivial on |0...0>
        __syncthreads();   // all gathers complete before slots are overwritten
        #pragma unroll
        for (int r = 0; r < 16; ++r) st[base0 ^ r] = v[r];
        __syncthreads();
        // G1 (wires 4-7): thread-private slot round trip
        #pragma unroll
        for (int r = 0; r < 16; ++r) v[r] = st[base1 ^ (17 * r)];
        apply4f(v, ub + 32, true, true);
        #pragma unroll
        for (int r = 0; r < 16; ++r) st[base1 ^ (17 * r)] = v[r];
        __syncthreads();
        // G2 (wires 8-11); final Phi skipped (|amp|^2 is phase-invariant)
        #pragma unroll
        for (int r = 0; r < 16; ++r) v[r] = st[base2 ^ (r << 8)];
        apply4f(v, ub + 64, true, L != 2);
        #pragma unroll
        for (int r = 0; r < 16; ++r) st[base2 ^ (r << 8)] = v[r];
        __syncthreads();
    }

    // ---- measurement (final CNOT ring folded into gather); amp c = (r<<8)|t
    float ztot = 0.f, z8 = 0.f, z9 = 0.f, z10 = 0.f, z11 = 0.f;
    #pragma unroll
    for (int r = 0; r < 16; ++r) {
        const v2f amp = st[mbase ^ mk(r)];
        const float pr = amp.x * amp.x + amp.y * amp.y;
        ztot += pr;
        z8  += (r & 1) ? -pr : pr;
        z9  += (r & 2) ? -pr : pr;
        z10 += (r & 4) ? -pr : pr;
        z11 += (r & 8) ? -pr : pr;
    }
    float zp[12];
    #pragma unroll
    for (int i = 0; i < 8; ++i)
        zp[i] = ((t >> i) & 1) ? -ztot : ztot;
    zp[8] = z8; zp[9] = z9; zp[10] = z10; zp[11] = z11;

    #pragma unroll
    for (int i = 0; i < 12; ++i) {
        float vv = zp[i];
        #pragma unroll
        for (int off = 32; off > 0; off >>= 1)
            vv += __shfl_xor(vv, off, 64);
        zp[i] = vv;
    }

    // ---- epilogue arrays alias into st (all statevector reads are done)
    __syncthreads();
    float* stf  = (float*)st;
    float* zred = stf;        // [4][12]
    float* qzs  = stf + 48;   // [12]
    float* hbuf = stf + 64;   // [64]

    const int wave = t >> 6;
    if ((t & 63) == 0) {
        #pragma unroll
        for (int i = 0; i < 12; ++i) zred[wave * 12 + i] = zp[i];
    }
    __syncthreads();
    if (t < 12)
        qzs[t] = zred[t] + zred[12 + t] + zred[24 + t] + zred[36 + t];
    __syncthreads();

    // ---- MLP head
    if (t < 64) {
        float acc = b1[t];
        #pragma unroll
        for (int i = 0; i < 12; ++i) acc += qzs[i] * w1[t * 12 + i];
        hbuf[t] = fmaxf(acc, 0.0f);
    }
    __syncthreads();
    float acc = b2[t];
    #pragma unroll 4   // cap outstanding float4 loads
    for (int k4 = 0; k4 < 16; ++k4) {
        const float4 wv = ((const float4*)w2)[t * 16 + k4];
        acc += wv.x * hbuf[k4 * 4 + 0] + wv.y * hbuf[k4 * 4 + 1]
             + wv.z * hbuf[k4 * 4 + 2] + wv.w * hbuf[k4 * 4 + 3];
    }
    out[b * 256 + t] = acc;
}

extern "C" void kernel_launch(void* const* d_in, const int* in_sizes, int n_in,
                              void* d_out, int out_size, void* d_ws, size_t ws_size,
                              hipStream_t stream) {
    const float* x  = (const float*)d_in[0];
    const float* rw = (const float*)d_in[1];
    const float* rb = (const float*)d_in[2];
    const float* w1 = (const float*)d_in[3];
    const float* b1 = (const float*)d_in[4];
    const float* w2 = (const float*)d_in[5];
    const float* b2 = (const float*)d_in[6];
    float* out = (float*)d_out;
    float* uws = (float*)d_ws;                    // [B*96] floats = 786432 B

    const int batch = in_sizes[0] / 48;           // x is [B,48]
    const int total3 = batch * 3;
    qparam_kernel<<<(total3 + 255) / 256, 256, 0, stream>>>(x, rw, rb, uws, total3);
    qreup_kernel<<<batch, 256, 0, stream>>>(uws, w1, b1, w2, b2, out);
}

// Round 11
// 124.081 us; speedup vs baseline: 1.0924x; 1.0924x over previous
//
#include <hip/hip_runtime.h>
#include <math.h>

// --- GF(2)-linear index helpers ---
// LDS bank swizzle: slot = i ^ ((i>>4)&15)  (involution)
__device__ __forceinline__ int sig(int i) { return i ^ ((i >> 4) & 15); }
// sig(finv(r)), r in [0,16): finv(c) = ((c ^ (c<<1)) & 0xFFF) ^ (bit11(c)*3)
__device__ __forceinline__ int gk(int r) {
    int j = (r ^ (r << 1)) & 0xFFF;
    return j ^ ((j >> 4) & 15);
}

// ---------- Kernel A: data-reupload params -> U3 matrices ----------
__global__ __attribute__((amdgpu_flat_work_group_size(256, 256)))
void qparam_kernel(const float* __restrict__ x, const float* __restrict__ rw,
                   const float* __restrict__ rb, float* __restrict__ uo, int total)
{
    const int g = blockIdx.x * 256 + threadIdx.x;   // g = b*12 + c
    if (g >= total) return;
    const int c = g % 12;
    const float4 xv = ((const float4*)x)[g];        // x viewed as [B,12,4]
    float prm[3];
    #pragma unroll
    for (int p = 0; p < 3; ++p) {
        const float4 wv = ((const float4*)rw)[c * 3 + p];
        prm[p] = rb[c * 3 + p] + wv.x * xv.x + wv.y * xv.y + wv.z * xv.z + wv.w * xv.w;
    }
    float st_, ct_; sincosf(0.5f * prm[0], &st_, &ct_);
    float sp_, cp_; sincosf(prm[1], &sp_, &cp_);
    float sl_, cl_; sincosf(prm[2], &sl_, &cl_);
    const float cpl = cp_ * cl_ - sp_ * sl_;
    const float spl = sp_ * cl_ + cp_ * sl_;
    // U3 row layout: {ct, 0, u01r, u01i, u10r, u10i, u11r, u11i}
    ((float4*)uo)[g * 2]     = make_float4(ct_, 0.0f, -cl_ * st_, -sl_ * st_);
    ((float4*)uo)[g * 2 + 1] = make_float4(cp_ * st_, sp_ * st_, cpl * ct_, spl * ct_);
}

// Apply 4 single-qubit gates (local bits 0..3) to a 16-amp register subcube.
// Coefficients in SGPRs (block-uniform loads). Scalar fmaf chains: sign
// structure folds into free VOP3 neg modifiers — no swap/shuffle ops at all.
__device__ __forceinline__ void apply4s(float2 v[16], const float* __restrict__ ub, int wbase) {
    #pragma unroll
    for (int g = 0; g < 4; ++g) {
        const float4 uA = ((const float4*)ub)[(wbase + g) * 2];
        const float4 uB = ((const float4*)ub)[(wbase + g) * 2 + 1];
        const float ct = uA.x, u01r = uA.z, u01i = uA.w;
        const float u10r = uB.x, u10i = uB.y, u11r = uB.z, u11i = uB.w;
        const int m = 1 << g;
        #pragma unroll
        for (int j = 0; j < 16; ++j) {
            if (j & m) continue;
            const float2 a0 = v[j], a1 = v[j | m];
            float2 n0, n1;
            n0.x = fmaf(ct, a0.x, fmaf(u01r, a1.x, -u01i * a1.y));
            n0.y = fmaf(ct, a0.y, fmaf(u01r, a1.y,  u01i * a1.x));
            n1.x = fmaf(u10r, a0.x, fmaf(-u10i, a0.y, fmaf(u11r, a1.x, -u11i * a1.y)));
            n1.y = fmaf(u10r, a0.y, fmaf( u10i, a0.x, fmaf(u11r, a1.y,  u11i * a1.x)));
            v[j]     = n0;
            v[j | m] = n1;
        }
    }
}

// ---------- Kernel B: statevector sim + measurement + MLP head ----------
__global__ __attribute__((amdgpu_flat_work_group_size(256, 256), amdgpu_waves_per_eu(4, 5)))
void qreup_kernel(const float* __restrict__ uin,  // [B,12,8] U3 matrices
                  const float* __restrict__ w1,   // [64,12]
                  const float* __restrict__ b1,   // [64]
                  const float* __restrict__ w2,   // [256,64]
                  const float* __restrict__ b2,   // [256]
                  float* __restrict__ out)        // [B,256]
{
    __shared__ float2 st[4096];                   // 32768 B, swizzled layout sig(i)

    const int t = threadIdx.x;
    const int b = blockIdx.x;
    const float* __restrict__ ub = uin + b * 96;  // block-uniform gate table

    // slot bases (GF(2)-linear decompositions of the swizzled layout)
    const int base0 = (t << 4) | (t & 15);         // G0: slot = base0 ^ j
    const int base1 = ((t >> 4) << 8) | (t & 15);  // G1: slot = base1 ^ (17j)
    const int base2 = t ^ (t >> 4);                // G2: slot = base2 ^ (j<<8)
    const int a_ = t << 4;                         // gather base: sig(finv(t<<4))
    const int gj = ((a_ ^ (a_ << 1)) & 0xFFF) ^ ((a_ >> 11) * 3);
    const int gbase = gj ^ ((gj >> 4) & 15);

    // measurement accumulators (written in the L==2 tail)
    float ptot = 0.f, zA = 0.f, z8 = 0.f, z9 = 0.f, z10 = 0.f;

    #pragma unroll 1
    for (int L = 0; L < 3; ++L) {
        float2 v[16];
        // G0 (wires 0-3); previous layer's CNOT ring folded into the gather
        if (L == 0) {
            #pragma unroll
            for (int r = 0; r < 16; ++r) v[r] = make_float2(0.0f, 0.0f);
            if (t == 0) v[0].x = 1.0f;
        } else {
            #pragma unroll
            for (int r = 0; r < 16; ++r) v[r] = st[gbase ^ gk(r)];
        }
        apply4s(v, ub, 0);
        if (L) __syncthreads();   // anti-dep: all gathers done before overwrite
        #pragma unroll
        for (int r = 0; r < 16; ++r) st[base0 ^ r] = v[r];
        // G0 store -> G1 load is CLUSTER-LOCAL (writer of amp a is thread a>>4,
        // reader is ((a>>8)<<4)|(a&15): same 16-thread cluster, same wave).
        // Per-wave LDS ops execute in order -> no __syncthreads needed.
        __builtin_amdgcn_wave_barrier();
        #pragma unroll
        for (int r = 0; r < 16; ++r) v[r] = st[base1 ^ (17 * r)];
        apply4s(v, ub, 4);
        #pragma unroll
        for (int r = 0; r < 16; ++r) st[base1 ^ (17 * r)] = v[r];
        __syncthreads();          // G1 -> G2 is cross-wave
        #pragma unroll
        for (int r = 0; r < 16; ++r) v[r] = st[base2 ^ (r << 8)];
        apply4s(v, ub, 8);
        if (L < 2) {
            #pragma unroll
            for (int r = 0; r < 16; ++r) st[base2 ^ (r << 8)] = v[r];
            __syncthreads();      // G2 store -> next layer's gather
        } else {
            // Final CNOT ring + measurement folded into registers:
            // post-CNOT index y = F(b): y_k = parity(b & (2^{k+1}-1)), y_0 = b_0^parity(b).
            // v[j] holds amp b = (j<<8)|t.
            #pragma unroll
            for (int j = 0; j < 16; ++j) {
                const float pr = v[j].x * v[j].x + v[j].y * v[j].y;
                ptot += pr;
                zA  += (__popc(j) & 1)     ? -pr : pr;   // parity(j)
                z8  += (j & 1)             ? -pr : pr;   // j0
                z9  += (__popc(j & 3) & 1) ? -pr : pr;   // j0^j1
                z10 += (__popc(j & 7) & 1) ? -pr : pr;   // j0^j1^j2
            }
        }
    }

    // zp[i] = sum over this thread's amps of (-1)^{F(b)_i} |amp|^2
    const int par_t = __popc(t) & 1;               // parity of bits 0..7
    float zp[12];
    zp[0] = ((t & 1) ^ par_t) ? -zA : zA;          // y0 = b0 ^ parity(all)
    #pragma unroll
    for (int k = 1; k < 8; ++k)                    // y_k = parity(t & (2^{k+1}-1))
        zp[k] = (__popc(t & ((2 << k) - 1)) & 1) ? -ptot : ptot;
    zp[8]  = par_t ? -z8  : z8;
    zp[9]  = par_t ? -z9  : z9;
    zp[10] = par_t ? -z10 : z10;
    zp[11] = par_t ? -zA  : zA;

    #pragma unroll
    for (int i = 0; i < 12; ++i) {
        float vv = zp[i];
        #pragma unroll
        for (int off = 32; off > 0; off >>= 1)
            vv += __shfl_xor(vv, off, 64);
        zp[i] = vv;
    }

    // ---- epilogue arrays alias into st (all statevector reads are done)
    __syncthreads();
    float* stf  = (float*)st;
    float* zred = stf;        // [4][12]
    float* qzs  = stf + 48;   // [12]
    float* hbuf = stf + 64;   // [64]

    const int wave = t >> 6;
    if ((t & 63) == 0) {
        #pragma unroll
        for (int i = 0; i < 12; ++i) zred[wave * 12 + i] = zp[i];
    }
    __syncthreads();
    if (t < 12)
        qzs[t] = zred[t] + zred[12 + t] + zred[24 + t] + zred[36 + t];
    __syncthreads();

    // ---- MLP head
    if (t < 64) {
        float acc = b1[t];
        #pragma unroll
        for (int i = 0; i < 12; ++i) acc += qzs[i] * w1[t * 12 + i];
        hbuf[t] = fmaxf(acc, 0.0f);
    }
    __syncthreads();
    float acc = b2[t];
    #pragma unroll 4   // cap outstanding float4 loads
    for (int k4 = 0; k4 < 16; ++k4) {
        const float4 wv = ((const float4*)w2)[t * 16 + k4];
        acc += wv.x * hbuf[k4 * 4 + 0] + wv.y * hbuf[k4 * 4 + 1]
             + wv.z * hbuf[k4 * 4 + 2] + wv.w * hbuf[k4 * 4 + 3];
    }
    out[b * 256 + t] = acc;
}

extern "C" void kernel_launch(void* const* d_in, const int* in_sizes, int n_in,
                              void* d_out, int out_size, void* d_ws, size_t ws_size,
                              hipStream_t stream) {
    const float* x  = (const float*)d_in[0];
    const float* rw = (const float*)d_in[1];
    const float* rb = (const float*)d_in[2];
    const float* w1 = (const float*)d_in[3];
    const float* b1 = (const float*)d_in[4];
    const float* w2 = (const float*)d_in[5];
    const float* b2 = (const float*)d_in[6];
    float* out = (float*)d_out;
    float* uws = (float*)d_ws;                    // [B*96] floats = 786432 B

    const int batch = in_sizes[0] / 48;           // x is [B,48]
    const int total = batch * 12;
    qparam_kernel<<<(total + 255) / 256, 256, 0, stream>>>(x, rw, rb, uws, total);
    qreup_kernel<<<batch, 256, 0, stream>>>(uws, w1, b1, w2, b2, out);
}